// Round 4
// baseline (66.787 us; speedup 1.0000x reference)
//
#include <hip/hip_runtime.h>

// Chamfer distance via MFMA, N=M=16384, D=3, f32.
// min_j dist(p,q_j) = -2 * ( max_j (dot(p,q_j) - 0.5|q_j|^2) - 0.5|p|^2 ), clamped >= 0.
// dot computed EXACTLY (to fp32 rounding) on the bf16 matrix pipe: each f32
// coord splits into 3 bf16 (hi,mid,lo = 24 mantissa bits); all 9 cross
// products per dim occupy K-slots k = dim*9 + s*3 + t (27 slots); slots
// 27..29 carry the 3-split of -0.5|q|^2 against 1.0 on the owner side.
// One mfma_f32_16x16x32_bf16 = 16 q's x 16 owners of (dot - 0.5|q|^2).
// Owners are B-columns: lane's 4 D-regs = 4 q-rows of one owner (C/D layout
// col=lane&15, row=(lane>>4)*4+reg), folded with 2 max3 per MFMA; final
// cross-lane max over the 4 row-groups via shfl_xor(16/32).

typedef short bf16x8 __attribute__((ext_vector_type(8)));  // 8 bf16 = 4 VGPR
typedef float f32x4 __attribute__((ext_vector_type(4)));

#define NPTS   16384
#define TPB    256
#define OT     16                 // owner 16-tiles per wave -> 256 owners/wave
#define SLICES 32                 // q slices; 512 q per slice
#define QSL    (NPTS / SLICES)    // 512
#define OPW    (OT * 16)          // 256 owners per wave
#define OWAVES (NPTS / OPW)       // 64 owner-waves per direction
#define WPB    4                  // waves per block

__device__ __forceinline__ unsigned short f2b(float f) {  // fp32 -> bf16 RNE
    union { float f; unsigned u; } a; a.f = f;
    return (unsigned short)((a.u + 0x7FFFu + ((a.u >> 16) & 1u)) >> 16);
}
__device__ __forceinline__ float b2f(unsigned short b) {
    union { unsigned u; float f; } a; a.u = ((unsigned)b) << 16;
    return a.f;
}

// Per point, build the A-role (q-side) and B-role (owner-side) 32-slot bf16
// k-vectors, the fp32 0.5|v|^2, and init the min array (every call: graph
// replay must be deterministic).
__global__ __launch_bounds__(TPB) void cd_prep(
        const float* __restrict__ x, const float* __restrict__ y,
        unsigned short* __restrict__ xA, unsigned short* __restrict__ xB,
        unsigned short* __restrict__ yA, unsigned short* __restrict__ yB,
        float* __restrict__ xh, float* __restrict__ yh,
        unsigned* __restrict__ minx, unsigned* __restrict__ miny, int n, int m) {
    int i = blockIdx.x * TPB + threadIdx.x;
    if (i >= n + m) return;
    const float* src = (i < n) ? x : y;
    int k = (i < n) ? i : i - n;
    unsigned short* A = (i < n) ? xA : yA;
    unsigned short* B = (i < n) ? xB : yB;
    float* h = (i < n) ? xh : yh;
    unsigned* mn = (i < n) ? minx : miny;

    float v[3] = { src[3 * k], src[3 * k + 1], src[3 * k + 2] };
    unsigned short sp[3][3];  // [dim][split]
#pragma unroll
    for (int d = 0; d < 3; ++d) {
        float r = v[d];
        sp[d][0] = f2b(r); r -= b2f(sp[d][0]);
        sp[d][1] = f2b(r); r -= b2f(sp[d][1]);
        sp[d][2] = f2b(r);
    }
    float half = 0.5f * (v[0] * v[0] + v[1] * v[1] + v[2] * v[2]);
    unsigned short ss[3];
    { float r = -half;
      ss[0] = f2b(r); r -= b2f(ss[0]);
      ss[1] = f2b(r); r -= b2f(ss[1]);
      ss[2] = f2b(r); }

    unsigned short Av[32], Bv[32];
#pragma unroll
    for (int j = 0; j < 32; ++j) { Av[j] = 0; Bv[j] = 0; }
#pragma unroll
    for (int d = 0; d < 3; ++d)
#pragma unroll
        for (int a = 0; a < 3; ++a)      // owner-split index
#pragma unroll
            for (int t = 0; t < 3; ++t) {  // q-split index
                Av[d * 9 + a * 3 + t] = sp[d][t];  // q side: repeat over a
                Bv[d * 9 + a * 3 + t] = sp[d][a];  // p side: repeat over t
            }
#pragma unroll
    for (int a = 0; a < 3; ++a) { Av[27 + a] = ss[a]; Bv[27 + a] = 0x3F80; }  // 1.0

    unsigned* Ao = (unsigned*)(A + (size_t)k * 32);
    unsigned* Bo = (unsigned*)(B + (size_t)k * 32);
#pragma unroll
    for (int j = 0; j < 16; ++j) {
        Ao[j] = (unsigned)Av[2 * j] | ((unsigned)Av[2 * j + 1] << 16);
        Bo[j] = (unsigned)Bv[2 * j] | ((unsigned)Bv[2 * j + 1] << 16);
    }
    h[k] = half;
    mn[k] = 0x7f800000u;  // +inf
}

// blockIdx.z = direction. Each wave: 256 owners (16 B-fragments resident in
// VGPRs) x one 512-q slice (32 A-tiles streamed from L2). Per A-tile: 1 load
// + 16 MFMA + 32 max3. Slice partials combined via uint atomicMin (distances
// >= 0 so float order == uint bit order).
__global__ __launch_bounds__(TPB, 4) void cd_pass(
        const unsigned short* __restrict__ xA, const unsigned short* __restrict__ xB,
        const unsigned short* __restrict__ yA, const unsigned short* __restrict__ yB,
        const float* __restrict__ xh, const float* __restrict__ yh,
        unsigned* __restrict__ minx, unsigned* __restrict__ miny) {
    const int lane = threadIdx.x & 63;
    const int wave = threadIdx.x >> 6;
    const int r = lane & 15, g = lane >> 4;

    const unsigned short* Aq; const unsigned short* Bp;
    const float* hs; unsigned* out;
    if (blockIdx.z == 0) { Aq = yA; Bp = xB; hs = xh; out = minx; }  // owners=x
    else                 { Aq = xA; Bp = yB; hs = yh; out = miny; }  // owners=y

    const int ow = blockIdx.x * WPB + wave;
    const int obase = ow * OPW;

    bf16x8 b[OT];
#pragma unroll
    for (int o = 0; o < OT; ++o)
        b[o] = *(const bf16x8*)(Bp + (size_t)(obase + o * 16 + r) * 32 + g * 8);

    float mx[OT];
#pragma unroll
    for (int o = 0; o < OT; ++o) mx[o] = -INFINITY;

    const int q0 = blockIdx.y * QSL;
    const f32x4 zero = {0.f, 0.f, 0.f, 0.f};
#pragma unroll 2
    for (int t = 0; t < QSL / 16; ++t) {
        bf16x8 a = *(const bf16x8*)(Aq + (size_t)(q0 + t * 16 + r) * 32 + g * 8);
#pragma unroll
        for (int o = 0; o < OT; ++o) {
            f32x4 d = __builtin_amdgcn_mfma_f32_16x16x32_bf16(a, b[o], zero, 0, 0, 0);
            mx[o] = fmaxf(mx[o], fmaxf(d[0], d[1]));  // -> v_max3
            mx[o] = fmaxf(mx[o], fmaxf(d[2], d[3]));
        }
    }

#pragma unroll
    for (int o = 0; o < OT; ++o) {
        float vv = mx[o];
        vv = fmaxf(vv, __shfl_xor(vv, 16, 64));
        vv = fmaxf(vv, __shfl_xor(vv, 32, 64));
        if (lane < 16) {
            int id = obase + o * 16 + lane;
            float dmin = fmaxf(0.0f, 2.0f * (hs[id] - vv));
            atomicMin(&out[id], __float_as_uint(dmin));
        }
    }
}

// Single-block final reduction: mean of minx[N] ++ miny[M].
__global__ __launch_bounds__(1024) void cd_reduce(const uint4* __restrict__ minx,
                                                  const uint4* __restrict__ miny,
                                                  float* __restrict__ out, int n, int mm) {
    float s = 0.0f;
    for (int i = threadIdx.x; i < n / 4; i += 1024) {
        uint4 v = minx[i];
        s += __uint_as_float(v.x) + __uint_as_float(v.y) +
             __uint_as_float(v.z) + __uint_as_float(v.w);
    }
    for (int i = threadIdx.x; i < mm / 4; i += 1024) {
        uint4 v = miny[i];
        s += __uint_as_float(v.x) + __uint_as_float(v.y) +
             __uint_as_float(v.z) + __uint_as_float(v.w);
    }
    for (int off = 32; off >= 1; off >>= 1) s += __shfl_down(s, off, 64);
    __shared__ float wsum[16];
    int wave = threadIdx.x >> 6;
    int lane = threadIdx.x & 63;
    if (lane == 0) wsum[wave] = s;
    __syncthreads();
    if (threadIdx.x == 0) {
        float t = 0.0f;
        for (int w = 0; w < 16; ++w) t += wsum[w];
        out[0] = t / (float)(n + mm);
    }
}

extern "C" void kernel_launch(void* const* d_in, const int* in_sizes, int n_in,
                              void* d_out, int out_size, void* d_ws, size_t ws_size,
                              hipStream_t stream) {
    const float* x = (const float*)d_in[0];
    const float* y = (const float*)d_in[1];
    const int N = in_sizes[0] / 3;  // 16384
    const int M = in_sizes[1] / 3;  // 16384

    unsigned short* xA = (unsigned short*)d_ws;     // N*32 bf16
    unsigned short* xB = xA + (size_t)N * 32;       // N*32
    unsigned short* yA = xB + (size_t)N * 32;       // M*32
    unsigned short* yB = yA + (size_t)M * 32;       // M*32
    float* xh = (float*)(yB + (size_t)M * 32);      // N f32
    float* yh = xh + N;                             // M f32
    unsigned* minx = (unsigned*)(yh + M);           // N uint
    unsigned* miny = minx + N;                      // M uint
    float* out = (float*)d_out;

    cd_prep<<<(N + M + TPB - 1) / TPB, TPB, 0, stream>>>(x, y, xA, xB, yA, yB,
                                                         xh, yh, minx, miny, N, M);

    // grid: (owner-wave groups, q slices, direction) = (16, 32, 2) = 1024 blocks
    cd_pass<<<dim3(OWAVES / WPB, SLICES, 2), TPB, 0, stream>>>(xA, xB, yA, yB,
                                                               xh, yh, minx, miny);

    cd_reduce<<<1, 1024, 0, stream>>>((const uint4*)minx, (const uint4*)miny, out, N, M);
}

// Round 5
// 57.102 us; speedup vs baseline: 1.1696x; 1.1696x over previous
//
#include <hip/hip_runtime.h>

// Chamfer distance via MFMA, N=M=16384, D=3, f32.
// min_j dist(p,q_j) = -2 * ( max_j (dot(p,q_j) - 0.5|q_j|^2) - 0.5|p|^2 ), clamped >= 0.
// dot computed EXACTLY (to fp32 rounding) on the bf16 matrix pipe: each f32
// coord splits into 3 bf16 (hi,mid,lo = 24 mantissa bits); all 9 cross
// products per dim occupy K-slots k = dim*9 + s*3 + t (27 slots); slots
// 27..29 carry the 3-split of -0.5|q|^2 against 1.0 on the owner side.
// One mfma_f32_16x16x32_bf16 = 16 q's x 16 owners of (dot - 0.5|q|^2).
// R4 changes vs R3: OT=8 so owner fragments provably fit arch VGPRs (R3's
// VGPR_Count=52 proved b[16] was not resident -> AGPR/reload traffic);
// A-slice staged in LDS once per block (shared by 4 waves, XOR-swizzled
// conflict-free) instead of per-wave L2 streams.

typedef short bf16x8 __attribute__((ext_vector_type(8)));  // 8 bf16 = 4 VGPR
typedef float f32x4 __attribute__((ext_vector_type(4)));

#define NPTS   16384
#define TPB    256
#define OT     8                  // owner 16-tiles per wave -> 128 owners/wave
#define OPW    (OT * 16)          // 128
#define OPB    (OPW * 4)          // 512 owners per block (4 waves)
#define SLICES 32                 // q slices
#define QSL    (NPTS / SLICES)    // 512 q per slice (32 KB LDS)

__device__ __forceinline__ unsigned short f2b(float f) {  // fp32 -> bf16 RNE
    union { float f; unsigned u; } a; a.f = f;
    return (unsigned short)((a.u + 0x7FFFu + ((a.u >> 16) & 1u)) >> 16);
}
__device__ __forceinline__ float b2f(unsigned short b) {
    union { unsigned u; float f; } a; a.u = ((unsigned)b) << 16;
    return a.f;
}

// Per point, build the A-role (q-side) and B-role (owner-side) 32-slot bf16
// k-vectors, the fp32 0.5|v|^2, and init the min array (every call: graph
// replay must be deterministic).
__global__ __launch_bounds__(TPB) void cd_prep(
        const float* __restrict__ x, const float* __restrict__ y,
        unsigned short* __restrict__ xA, unsigned short* __restrict__ xB,
        unsigned short* __restrict__ yA, unsigned short* __restrict__ yB,
        float* __restrict__ xh, float* __restrict__ yh,
        unsigned* __restrict__ minx, unsigned* __restrict__ miny, int n, int m) {
    int i = blockIdx.x * TPB + threadIdx.x;
    if (i >= n + m) return;
    const float* src = (i < n) ? x : y;
    int k = (i < n) ? i : i - n;
    unsigned short* A = (i < n) ? xA : yA;
    unsigned short* B = (i < n) ? xB : yB;
    float* h = (i < n) ? xh : yh;
    unsigned* mn = (i < n) ? minx : miny;

    float v[3] = { src[3 * k], src[3 * k + 1], src[3 * k + 2] };
    unsigned short sp[3][3];  // [dim][split]
#pragma unroll
    for (int d = 0; d < 3; ++d) {
        float r = v[d];
        sp[d][0] = f2b(r); r -= b2f(sp[d][0]);
        sp[d][1] = f2b(r); r -= b2f(sp[d][1]);
        sp[d][2] = f2b(r);
    }
    float half = 0.5f * (v[0] * v[0] + v[1] * v[1] + v[2] * v[2]);
    unsigned short ss[3];
    { float r = -half;
      ss[0] = f2b(r); r -= b2f(ss[0]);
      ss[1] = f2b(r); r -= b2f(ss[1]);
      ss[2] = f2b(r); }

    unsigned short Av[32], Bv[32];
#pragma unroll
    for (int j = 0; j < 32; ++j) { Av[j] = 0; Bv[j] = 0; }
#pragma unroll
    for (int d = 0; d < 3; ++d)
#pragma unroll
        for (int a = 0; a < 3; ++a)        // owner-split index
#pragma unroll
            for (int t = 0; t < 3; ++t) {  // q-split index
                Av[d * 9 + a * 3 + t] = sp[d][t];  // q side: repeat over a
                Bv[d * 9 + a * 3 + t] = sp[d][a];  // p side: repeat over t
            }
#pragma unroll
    for (int a = 0; a < 3; ++a) { Av[27 + a] = ss[a]; Bv[27 + a] = 0x3F80; }  // 1.0

    unsigned* Ao = (unsigned*)(A + (size_t)k * 32);
    unsigned* Bo = (unsigned*)(B + (size_t)k * 32);
#pragma unroll
    for (int j = 0; j < 16; ++j) {
        Ao[j] = (unsigned)Av[2 * j] | ((unsigned)Av[2 * j + 1] << 16);
        Bo[j] = (unsigned)Bv[2 * j] | ((unsigned)Bv[2 * j + 1] << 16);
    }
    h[k] = half;
    mn[k] = 0x7f800000u;  // +inf
}

// blockIdx = (owner-block, q-slice, direction). Each block stages its 512-q
// A-slice into LDS (XOR-swizzled: byte ^= (row&7)<<4 -> conflict-free b128
// reads AND float4 writes), then each wave runs 128 resident owners x 32
// A-tiles: per tile 1 ds_read_b128 + 8 MFMA + 16 v_max3. Slice partials via
// uint atomicMin (distances >= 0 so float order == uint bit order).
__global__ __launch_bounds__(TPB, 4) void cd_pass(
        const unsigned short* __restrict__ xA, const unsigned short* __restrict__ xB,
        const unsigned short* __restrict__ yA, const unsigned short* __restrict__ yB,
        const float* __restrict__ xh, const float* __restrict__ yh,
        unsigned* __restrict__ minx, unsigned* __restrict__ miny) {
    __shared__ __align__(16) char As[QSL * 64];

    const int lane = threadIdx.x & 63;
    const int wave = threadIdx.x >> 6;
    const int r = lane & 15, g = lane >> 4;

    const unsigned short* Aq; const unsigned short* Bp;
    const float* hs; unsigned* out;
    if (blockIdx.z == 0) { Aq = yA; Bp = xB; hs = xh; out = minx; }  // owners=x
    else                 { Aq = xA; Bp = yB; hs = yh; out = miny; }  // owners=y

    // Stage A slice -> LDS (swizzled). 2048 16B-chunks, 256 threads, 8 iters.
    const int q0 = blockIdx.y * QSL;
#pragma unroll
    for (int it = 0; it < (QSL * 4) / TPB; ++it) {
        int idx = it * TPB + threadIdx.x;
        int row = idx >> 2, gg = idx & 3;
        float4 v = *(const float4*)(Aq + (size_t)(q0 + row) * 32 + gg * 8);
        *(float4*)(As + ((row * 64 + gg * 16) ^ ((row & 7) << 4))) = v;
    }
    __syncthreads();

    const int obase = blockIdx.x * OPB + wave * OPW;
    bf16x8 b[OT];
    float mx[OT];
#pragma unroll
    for (int o = 0; o < OT; ++o) {
        b[o] = *(const bf16x8*)(Bp + (size_t)(obase + o * 16 + r) * 32 + g * 8);
        mx[o] = -INFINITY;
    }

    // Per-lane LDS read address: row = t*16 + r (row&7 == r&7), chunk g.
    const int lbase = (r * 64 + g * 16) ^ ((r & 7) << 4);
    const f32x4 zero = {0.f, 0.f, 0.f, 0.f};
#pragma unroll 2
    for (int t = 0; t < QSL / 16; ++t) {
        bf16x8 a = *(const bf16x8*)(As + lbase + t * 1024);
#pragma unroll
        for (int o = 0; o < OT; ++o) {
            f32x4 d = __builtin_amdgcn_mfma_f32_16x16x32_bf16(a, b[o], zero, 0, 0, 0);
            mx[o] = fmaxf(mx[o], fmaxf(d[0], d[1]));  // -> v_max3
            mx[o] = fmaxf(mx[o], fmaxf(d[2], d[3]));
        }
    }

#pragma unroll
    for (int o = 0; o < OT; ++o) {
        float vv = mx[o];
        vv = fmaxf(vv, __shfl_xor(vv, 16, 64));
        vv = fmaxf(vv, __shfl_xor(vv, 32, 64));
        if (lane < 16) {
            int id = obase + o * 16 + lane;
            float dmin = fmaxf(0.0f, 2.0f * (hs[id] - vv));
            atomicMin(&out[id], __float_as_uint(dmin));
        }
    }
}

// Single-block final reduction: mean of minx[N] ++ miny[M].
__global__ __launch_bounds__(1024) void cd_reduce(const uint4* __restrict__ minx,
                                                  const uint4* __restrict__ miny,
                                                  float* __restrict__ out, int n, int mm) {
    float s = 0.0f;
    for (int i = threadIdx.x; i < n / 4; i += 1024) {
        uint4 v = minx[i];
        s += __uint_as_float(v.x) + __uint_as_float(v.y) +
             __uint_as_float(v.z) + __uint_as_float(v.w);
    }
    for (int i = threadIdx.x; i < mm / 4; i += 1024) {
        uint4 v = miny[i];
        s += __uint_as_float(v.x) + __uint_as_float(v.y) +
             __uint_as_float(v.z) + __uint_as_float(v.w);
    }
    for (int off = 32; off >= 1; off >>= 1) s += __shfl_down(s, off, 64);
    __shared__ float wsum[16];
    int wave = threadIdx.x >> 6;
    int lane = threadIdx.x & 63;
    if (lane == 0) wsum[wave] = s;
    __syncthreads();
    if (threadIdx.x == 0) {
        float t = 0.0f;
        for (int w = 0; w < 16; ++w) t += wsum[w];
        out[0] = t / (float)(n + mm);
    }
}

extern "C" void kernel_launch(void* const* d_in, const int* in_sizes, int n_in,
                              void* d_out, int out_size, void* d_ws, size_t ws_size,
                              hipStream_t stream) {
    const float* x = (const float*)d_in[0];
    const float* y = (const float*)d_in[1];
    const int N = in_sizes[0] / 3;  // 16384
    const int M = in_sizes[1] / 3;  // 16384

    unsigned short* xA = (unsigned short*)d_ws;     // N*32 bf16
    unsigned short* xB = xA + (size_t)N * 32;       // N*32
    unsigned short* yA = xB + (size_t)N * 32;       // M*32
    unsigned short* yB = yA + (size_t)M * 32;       // M*32
    float* xh = (float*)(yB + (size_t)M * 32);      // N f32
    float* yh = xh + N;                             // M f32
    unsigned* minx = (unsigned*)(yh + M);           // N uint
    unsigned* miny = minx + N;                      // M uint
    float* out = (float*)d_out;

    cd_prep<<<(N + M + TPB - 1) / TPB, TPB, 0, stream>>>(x, y, xA, xB, yA, yB,
                                                         xh, yh, minx, miny, N, M);

    // grid: (owner blocks, q slices, direction) = (32, 32, 2) = 2048 blocks
    cd_pass<<<dim3(NPTS / OPB, SLICES, 2), TPB, 0, stream>>>(xA, xB, yA, yB,
                                                             xh, yh, minx, miny);

    cd_reduce<<<1, 1024, 0, stream>>>((const uint4*)minx, (const uint4*)miny, out, N, M);
}